// Round 16
// baseline (251.180 us; speedup 1.0000x reference)
//
#include <hip/hip_runtime.h>
#include <math.h>

// GCN1: 2x SplineConv (deg-1 B-spline, KS=5, dim=2) + graclus max-pools + MLP head.
#define NN_F1 32
#define NN_F2 64
#define NN_FH 128
#define NN_NC 10
#define NN_NG 50
#define ACCI 808           // int32 A-row stride (800 used + 8 pad)
#define FXS  1048576.0f    // 2^20 fixed-point scale (conv scatters)
#define FXI  (1.0f/1048576.0f)
#define GXS  65536.0f      // 2^16 fixed-point scale (graph mean-pool)
#define GXI  (1.0f/65536.0f)

typedef __attribute__((ext_vector_type(8))) short short8v;   // 8 bf16 = 4 VGPRs
typedef __attribute__((ext_vector_type(4))) float f32x4;

// ---------- helpers ----------
__device__ __forceinline__ unsigned fkey(float f) {
    unsigned u = __float_as_uint(f);
    return (u & 0x80000000u) ? ~u : (u | 0x80000000u);
}
__device__ __forceinline__ float funkey(unsigned k) {
    return (k & 0x80000000u) ? __uint_as_float(k & 0x7fffffffu) : __uint_as_float(~k);
}
// pack two floats -> two bf16 (RNE)
__device__ __forceinline__ unsigned bfp2(float a, float b) {
    unsigned ua = __float_as_uint(a), ub = __float_as_uint(b);
    ua += 0x7fffu + ((ua >> 16) & 1u);
    ub += 0x7fffu + ((ub >> 16) & 1u);
    return (ua >> 16) | (ub & 0xffff0000u);
}
__device__ __forceinline__ unsigned short bf1(float a) {
    unsigned u = __float_as_uint(a);
    u += 0x7fffu + ((u >> 16) & 1u);
    return (unsigned short)(u >> 16);
}

// degree-1 open B-spline, KS=5/dim, dim=2 — FLAT taps + products.
// Order matches reference reshape (verified rounds 0-15).
__device__ __forceinline__ void spline_basis(float ax, float ay, int wi[4], float bb[4]) {
    float v0 = ax * 4.0f, v1 = ay * 4.0f;
    float l0 = floorf(v0), l1 = floorf(v1);
    float f0 = v0 - l0, f1 = v1 - l1;
    int i0a = (int)l0, i1a = (int)l1;
    int i00 = min(max(i0a, 0), 4), i01 = min(max(i0a + 1, 0), 4);
    int i10 = min(max(i1a, 0), 4), i11 = min(max(i1a + 1, 0), 4);
    float b00 = 1.0f - f0, b01 = f0, b10 = 1.0f - f1, b11 = f1;
    wi[0] = i00 + 5 * i10; bb[0] = b00 * b10;
    wi[1] = i00 + 5 * i11; bb[1] = b00 * b11;
    wi[2] = i01 + 5 * i10; bb[2] = b01 * b10;
    wi[3] = i01 + 5 * i11; bb[3] = b01 * b11;
}

// ---------- K0: fused prep — both CSR indptrs + W2/root2 bf16 transpose ----------
__global__ __launch_bounds__(256) void k_prep(
    const int* __restrict__ row1, int E, int* __restrict__ ip1,
    const int* __restrict__ row2, int E2, int* __restrict__ ip2,
    const float* __restrict__ W2, const float* __restrict__ root2,
    unsigned short* __restrict__ W2T, unsigned short* __restrict__ r2T, int N)
{
    int i = blockIdx.x * 256 + threadIdx.x;
    if (i <= N) {
        if (i == N) { ip1[N] = E; ip2[N] = E2; }
        else {
            int l = 0, r = E;
            while (l < r) { int m = (l + r) >> 1; if (row1[m] < i) l = m + 1; else r = m; }
            ip1[i] = l;
            l = 0; r = E2;
            while (l < r) { int m = (l + r) >> 1; if (row2[m] < i) l = m + 1; else r = m; }
            ip2[i] = l;
        }
    }
    if (i < 800 * 64) {
        int k = i >> 6, n = i & 63;
        W2T[n * 800 + k] = bf1(W2[i]);
    } else if (i < 800 * 64 + 64 * 32) {
        int j = i - 800 * 64;
        int o = j >> 5, f = j & 31;
        r2T[o * 32 + f] = bf1(root2[f * 64 + o]);
    }
}

// ---------- K1: conv1, two-phase, 512 threads / 128-node tile ----------
__device__ __forceinline__ void scat1(int* __restrict__ gacc, int r,
                                      float2 ea, float xs) {
    int wi[4]; float bb[4];
    spline_basis(1.0f - ea.x, 1.0f - ea.y, wi, bb);
    int* bp = gacc + r * 26;
    atomicAdd((unsigned*)(bp + wi[0]), (unsigned)(int)(bb[0] * xs));
    atomicAdd((unsigned*)(bp + wi[1]), (unsigned)(int)(bb[1] * xs));
    atomicAdd((unsigned*)(bp + wi[2]), (unsigned)(int)(bb[2] * xs));
    atomicAdd((unsigned*)(bp + wi[3]), (unsigned)(int)(bb[3] * xs));
}
__global__ __launch_bounds__(512) void k_conv1(
    const float* __restrict__ x, const float* __restrict__ pos,
    const float* __restrict__ eattr,
    const int* __restrict__ ei0, const int* __restrict__ ei1,
    const int* __restrict__ indptr,
    const float* __restrict__ W1, const float* __restrict__ root1,
    const float* __restrict__ b1, const int* __restrict__ cluster1,
    unsigned* __restrict__ x2bits, unsigned* __restrict__ cnt1,
    float* __restrict__ possum, unsigned* __restrict__ n2slot, int N)
{
    __shared__ float w1s[25 * NN_F1];
    __shared__ float r1s[NN_F1], b1s[NN_F1];
    __shared__ int   gacc[128 * 26];      // fixed-point taps, stride 26 (bank-spread)
    __shared__ float invdeg[128], xds[128];
    __shared__ int   cls[128];
    __shared__ unsigned blkmax;
    int t = threadIdx.x;
    for (int i = t; i < 25 * NN_F1; i += 512) w1s[i] = W1[i];
    if (t < NN_F1) { r1s[t] = root1[t]; b1s[t] = b1[t]; }
    if (t == 0) blkmax = 0u;
    int4* gz = (int4*)gacc;
    for (int i = t; i < 128 * 26 / 4; i += 512) gz[i] = make_int4(0, 0, 0, 0);
    __syncthreads();                      // gacc zeroed, blkmax=0 visible

    int nb0 = blockIdx.x * 128;
    if (t < 128) {
        int d = nb0 + t;
        if (d < N) {
            int lo = indptr[d], hi = indptr[d + 1];
            invdeg[t] = FXI / (float)max(hi - lo, 1);   // descale folded in
            xds[t] = x[d];
            int c = cluster1[d];
            cls[t] = c;
            atomicAdd(&cnt1[c], 1u);
            atomicAdd(&possum[2 * c], pos[2 * d]);
            atomicAdd(&possum[2 * c + 1], pos[2 * d + 1]);
            atomicMax(&blkmax, (unsigned)c);
        }
    }

    // edge-parallel scatter over the block's contiguous CSR range, 2x unrolled
    int e0 = indptr[nb0], e1 = indptr[min(nb0 + 128, N)];
    int e = e0 + t;
    for (; e + 512 < e1; e += 1024) {
        int ra = ei0[e] - nb0,       sa = ei1[e];
        int rb = ei0[e + 512] - nb0, sb = ei1[e + 512];
        float2 eaa = ((const float2*)eattr)[e];
        float2 eab = ((const float2*)eattr)[e + 512];
        float xa = x[sa] * FXS;
        float xb = x[sb] * FXS;
        scat1(gacc, ra, eaa, xa);
        scat1(gacc, rb, eab, xb);
    }
    if (e < e1) {
        int ra = ei0[e] - nb0, sa = ei1[e];
        scat1(gacc, ra, ((const float2*)eattr)[e], x[sa] * FXS);
    }
    __syncthreads();                      // scatter + node-init complete
    if (t == 0) atomicMax(n2slot, blkmax);

    // Phase B: 16 groups x 32 lanes; lane o owns output feature o.
    int grp = t >> 5, o = t & 31;
    float wreg[25];
#pragma unroll
    for (int k = 0; k < 25; ++k) wreg[k] = w1s[k * NN_F1 + o];
    float ro = r1s[o], bo = b1s[o];
    int nloc = min(128, N - nb0);
    for (int i = grp; i < nloc; i += 16) {
        float a = 0.f;
#pragma unroll
        for (int k = 0; k < 25; ++k) a += (float)gacc[i * 26 + k] * wreg[k];
        float h = a * invdeg[i] + xds[i] * ro + bo;
        h = h > 0.f ? h : expm1f(h);
        atomicMax(&x2bits[(size_t)cls[i] * NN_F1 + o], fkey(h));
    }
}

// ---------- K2: finalize x2 -> bf16 (zero empties), pos2 = possum/cnt ----------
__global__ __launch_bounds__(256) void k_fin1(const unsigned* __restrict__ x2b,
                                              const unsigned* __restrict__ cnt1,
                                              unsigned short* __restrict__ x2bf,
                                              float* __restrict__ possum, int N)
{
    int i = blockIdx.x * 256 + threadIdx.x;
    int n = i >> 5, o = i & 31;
    if (n >= N) return;
    unsigned cnt = cnt1[n];
    float v = cnt ? funkey(x2b[i]) : 0.0f;
    x2bf[i] = bf1(v);
    if (o < 2) {
        float p = possum[2 * n + o];
        possum[2 * n + o] = p / (float)max(cnt, 1u);
    }
}

// ---------- K3: global max|cart| over pooled edges (block-reduced, 1 atomic/block) ----------
__global__ __launch_bounds__(256) void k_maxabs(const int* __restrict__ r0,
                                                const int* __restrict__ r1, int E2,
                                                const float* __restrict__ pos2,
                                                unsigned* __restrict__ maxbits)
{
    __shared__ float wmax[4];
    float m = 0.f;
    for (int e = blockIdx.x * 256 + threadIdx.x; e < E2; e += gridDim.x * 256) {
        int a = r0[e], b = r1[e];
        float cx = pos2[2 * a] - pos2[2 * b];
        float cy = pos2[2 * a + 1] - pos2[2 * b + 1];
        m = fmaxf(m, fmaxf(fabsf(cx), fabsf(cy)));
    }
    for (int off = 32; off; off >>= 1) m = fmaxf(m, __shfl_down(m, off));
    if ((threadIdx.x & 63) == 0) wmax[threadIdx.x >> 6] = m;
    __syncthreads();
    if (threadIdx.x == 0) {
        m = fmaxf(fmaxf(wmax[0], wmax[1]), fmaxf(wmax[2], wmax[3]));
        atomicMax(maxbits, __float_as_uint(m));   // all values >= 0: bit-compare ok
    }
}

// ---------- K3c: per-edge basis records (32B): {bb*2^20 f32x4, s, wjpack, d, pad} ----------
__global__ __launch_bounds__(256) void k_basis(
    const int* __restrict__ r0, const int* __restrict__ r1, int E2,
    const float* __restrict__ pos2, const unsigned* __restrict__ scal,
    float* __restrict__ rec)
{
    int e = blockIdx.x * 256 + threadIdx.x;
    if (e >= E2) return;
    float denom = 2.0f * __uint_as_float(scal[1]);
    int d = r0[e], s = r1[e];          // true edge is (s -> d): cart = pos2[s] - pos2[d]
    float ax = (pos2[2 * s] - pos2[2 * d]) / denom + 0.5f;
    float ay = (pos2[2 * s + 1] - pos2[2 * d + 1]) / denom + 0.5f;
    int wi[4]; float bb[4];
    spline_basis(ax, ay, wi, bb);
    unsigned wj = (unsigned)wi[0] | ((unsigned)wi[1] << 8)
                | ((unsigned)wi[2] << 16) | ((unsigned)wi[3] << 24);
    float* rp = rec + (size_t)e * 8;
    *(float4*)rp = make_float4(bb[0] * FXS, bb[1] * FXS, bb[2] * FXS, bb[3] * FXS);
    int4 meta = make_int4(s, (int)wj, d, 0);
    *(int4*)(rp + 4) = meta;
}

// ---------- K4: conv2 PERSISTENT producer-consumer pipeline ----------
// 256 persistent blocks (1/CU), 1024 threads, DOUBLE-BUFFERED 16-node A-tiles
// (2 x 51.7 KB = 103.4 KB LDS; 128 KB plain-HIP LDS proven on gfx950).
// Per iteration k (two barriers):
//   stage A: all threads zero buf[k&1]          (buf last read by GEMM k-1)
//   stage B: waves 4-15 scatter tile k -> buf[k&1]   (48 subgroups x 16 lanes)
//            CONCURRENTLY waves 0-3 GEMM+epilogue tile k-1 from buf[(k-1)&1]
// This replaces the old serial scatter->barrier->GEMM per block (whose 4-wave
// GEMM phases created CU starvation windows) with steady 12-producer/4-consumer
// overlap. Each block owns a CONTIGUOUS chunk of ~13 tiles (pipeline fill cost
// <10%). Scatter/GEMM internals identical to the r13-verified forms.
__device__ __forceinline__ short8v ld_frag(const unsigned short* p) {
    short8v a;
    ((unsigned long long*)&a)[0] = *(const unsigned long long*)(p);        // k+0..3
    ((unsigned long long*)&a)[1] = *(const unsigned long long*)(p + 16);   // k+16..19
    return a;
}
__device__ __forceinline__ short8v pack_frag_i(int4 a, int4 b) {
    union { unsigned u[4]; short8v s; } r;
    r.u[0] = bfp2((float)a.x * FXI, (float)a.y * FXI);
    r.u[1] = bfp2((float)a.z * FXI, (float)a.w * FXI);
    r.u[2] = bfp2((float)b.x * FXI, (float)b.y * FXI);
    r.u[3] = bfp2((float)b.z * FXI, (float)b.w * FXI);
    return r.s;
}
__device__ __forceinline__ void scat2(int* __restrict__ accs, int r, unsigned wj,
                                      float4 bb, float xl, float xh, int f2) {
    int* base = accs + r * ACCI + f2;
    int* a0 = base + ((wj & 31u) << 5);
    int* a1 = base + (((wj >> 8) & 31u) << 5);
    int* a2 = base + (((wj >> 16) & 31u) << 5);
    int* a3 = base + (((wj >> 24) & 31u) << 5);
    atomicAdd((unsigned*)a0,       (unsigned)(int)(bb.x * xl));
    atomicAdd((unsigned*)(a0 + 1), (unsigned)(int)(bb.x * xh));
    atomicAdd((unsigned*)a1,       (unsigned)(int)(bb.y * xl));
    atomicAdd((unsigned*)(a1 + 1), (unsigned)(int)(bb.y * xh));
    atomicAdd((unsigned*)a2,       (unsigned)(int)(bb.z * xl));
    atomicAdd((unsigned*)(a2 + 1), (unsigned)(int)(bb.z * xh));
    atomicAdd((unsigned*)a3,       (unsigned)(int)(bb.w * xl));
    atomicAdd((unsigned*)(a3 + 1), (unsigned)(int)(bb.w * xh));
}
__global__ __launch_bounds__(1024) void k_conv2(
    const float* __restrict__ rec, const int* __restrict__ indptr2,
    const unsigned short* __restrict__ x2bf, const unsigned short* __restrict__ W2T,
    const unsigned short* __restrict__ r2T, const float* __restrict__ b2,
    const int* __restrict__ cluster2, unsigned* __restrict__ x3bits,
    const unsigned* __restrict__ scal, int N)
{
    __shared__ int accs[2][16 * ACCI];    // double-buffered A-tiles (103.4 KB)
    int n2 = (int)scal[0] + 1;
    int A = (n2 + 15) >> 4;               // active tiles
    int chunk = (A + (int)gridDim.x - 1) / (int)gridDim.x;
    int t0 = blockIdx.x * chunk;
    int t1 = min(t0 + chunk, A);
    int nt = t1 - t0;
    if (nt <= 0) return;                  // block-uniform exit (no barriers yet)
    int t = threadIdx.x;

    for (int k = 0; k <= nt; ++k) {
        // ---- stage A: zero the scatter buffer (all 1024 threads) ----
        if (k < nt) {
            int4* bz = (int4*)accs[k & 1];
            for (int j = t; j < 16 * ACCI / 4; j += 1024)
                bz[j] = make_int4(0, 0, 0, 0);
        }
        __syncthreads();

        // ---- stage B: scatter tile k  ||  GEMM tile k-1 ----
        if (t >= 256) {
            if (k < nt) {
                int nb = (t0 + k) * 16;
                int* buf = accs[k & 1];
                int sg = (t - 256) >> 4, f2 = (t & 15) << 1;
                int e0 = indptr2[nb];
                int e1 = indptr2[min(nb + 16, N)];
                int len = ((e1 - e0) + 47) / 48;   // slice per subgroup
                int lo = e0 + sg * len;
                int hi = min(lo + len, e1);
                int e = lo;
                for (; e + 2 <= hi; e += 2) {
                    const float* rp0 = rec + (size_t)e * 8;
                    const float* rp1 = rp0 + 8;
                    float4 bb0 = *(const float4*)rp0;
                    int4  m0  = *(const int4*)(rp0 + 4);
                    float4 bb1 = *(const float4*)rp1;
                    int4  m1  = *(const int4*)(rp1 + 4);
                    unsigned xa = *(const unsigned*)(x2bf + (size_t)m0.x * 32 + f2);
                    unsigned xb = *(const unsigned*)(x2bf + (size_t)m1.x * 32 + f2);
                    float xla = __uint_as_float(xa << 16);
                    float xha = __uint_as_float(xa & 0xffff0000u);
                    float xlb = __uint_as_float(xb << 16);
                    float xhb = __uint_as_float(xb & 0xffff0000u);
                    scat2(buf, m0.z - nb, (unsigned)m0.y, bb0, xla, xha, f2);
                    scat2(buf, m1.z - nb, (unsigned)m1.y, bb1, xlb, xhb, f2);
                }
                if (e < hi) {
                    const float* rp0 = rec + (size_t)e * 8;
                    float4 bb0 = *(const float4*)rp0;
                    int4  m0  = *(const int4*)(rp0 + 4);
                    unsigned xa = *(const unsigned*)(x2bf + (size_t)m0.x * 32 + f2);
                    float xla = __uint_as_float(xa << 16);
                    float xha = __uint_as_float(xa & 0xffff0000u);
                    scat2(buf, m0.z - nb, (unsigned)m0.y, bb0, xla, xha, f2);
                }
            }
        } else if (k >= 1) {
            int nb = (t0 + k - 1) * 16;
            const int* buf = accs[(k - 1) & 1];
            int w = t >> 6, l = t & 63;
            int lg = l >> 4, lr = l & 15;
            int c0 = w * 16;
            const int* arow = buf + lr * ACCI;
            const unsigned short* pb = W2T + (size_t)(c0 + lr) * 800 + 4 * lg;

            f32x4 s4 = {0.f, 0.f, 0.f, 0.f};
            for (int kk = 0; kk < 800; kk += 32) {
                int4 a0 = *(const int4*)(arow + kk + 4 * lg);
                int4 a1 = *(const int4*)(arow + kk + 16 + 4 * lg);
                short8v af = pack_frag_i(a0, a1);
                short8v bf = ld_frag(pb + kk);
                s4 = __builtin_amdgcn_mfma_f32_16x16x32_bf16(af, bf, s4, 0, 0, 0);
            }

            int r0g = nb + 4 * lg;
#pragma unroll
            for (int i = 0; i < 4; ++i) {
                int gr = r0g + i;
                float invd = 0.0f;
                if (gr < n2)
                    invd = 1.0f / (float)max(indptr2[gr + 1] - indptr2[gr], 1);
                s4[i] *= invd;
            }
            int ar2 = nb + lr; if (ar2 > N - 1) ar2 = N - 1;
            short8v a2f = ld_frag(x2bf + (size_t)ar2 * 32 + 4 * lg);
            s4 = __builtin_amdgcn_mfma_f32_16x16x32_bf16(
                     a2f, ld_frag(r2T + (size_t)(c0 + lr) * 32 + 4 * lg), s4, 0, 0, 0);

            float bs = b2[c0 + lr];
#pragma unroll
            for (int i = 0; i < 4; ++i) {
                int gr = r0g + i;
                if (gr >= n2) continue;
                float h = s4[i] + bs;
                h = h > 0.f ? h : expm1f(h);
                atomicMax(&x3bits[(size_t)cluster2[gr] * 64 + c0 + lr], fkey(h));
            }
        }
        __syncthreads();
    }
}

// ---------- K6: graph mean-pool (INT fixed-point LDS histogram, native atomics) ----------
__global__ __launch_bounds__(256) void k_gsum(const unsigned* __restrict__ x3bits,
                                              const int* __restrict__ batch3,
                                              int* __restrict__ sbuf,
                                              unsigned* __restrict__ cbuf, int N)
{
    __shared__ int sl[NN_NG * 64];
    __shared__ unsigned clh[NN_NG];
    int t = threadIdx.x;
    for (int i = t; i < NN_NG * 64; i += 256) sl[i] = 0;
    if (t < NN_NG) clh[t] = 0u;
    __syncthreads();
    int o = t & 63, rsub = t >> 6;
    for (int i0 = blockIdx.x * 4; i0 < N; i0 += gridDim.x * 4) {
        int i = i0 + rsub;
        if (i < N) {
            int g = batch3[i];
            if (g < NN_NG) {   // dummy graph id NG is dropped
                float v = funkey(x3bits[(size_t)i * 64 + o]);
                atomicAdd((unsigned*)&sl[g * 64 + o], (unsigned)(int)(v * GXS));
                if (o == 0) atomicAdd(&clh[g], 1u);
            }
        }
    }
    __syncthreads();
    for (int i = t; i < NN_NG * 64; i += 256)
        atomicAdd((unsigned*)&sbuf[i], (unsigned)sl[i]);
    if (t < NN_NG) atomicAdd(&cbuf[t], clh[t]);
}

// ---------- K7: MLP head + log_softmax ----------
__global__ __launch_bounds__(128) void k_head(const int* __restrict__ sbuf,
                                              const unsigned* __restrict__ cbuf,
                                              const float* __restrict__ fc1w,
                                              const float* __restrict__ fc1b,
                                              const float* __restrict__ fc2w,
                                              const float* __restrict__ fc2b,
                                              float* __restrict__ out)
{
    __shared__ float xg[64], hl[NN_FH], ll[NN_NC];
    int g = blockIdx.x, t = threadIdx.x;
    if (t < 64) xg[t] = (float)sbuf[g * 64 + t] * GXI / (float)max(cbuf[g], 1u);
    __syncthreads();
    float a = fc1b[t];
    for (int f = 0; f < 64; ++f) a += xg[f] * fc1w[f * NN_FH + t];
    hl[t] = a > 0.f ? a : expm1f(a);
    __syncthreads();
    if (t < NN_NC) {
        float l = fc2b[t];
        for (int h = 0; h < NN_FH; ++h) l += hl[h] * fc2w[h * NN_NC + t];
        ll[t] = l;
    }
    __syncthreads();
    if (t < NN_NC) {
        float m = ll[0];
        for (int j = 1; j < NN_NC; ++j) m = fmaxf(m, ll[j]);
        float sum = 0.f;
        for (int j = 0; j < NN_NC; ++j) sum += expf(ll[j] - m);
        out[g * NN_NC + t] = ll[t] - m - logf(sum);
    }
}

// ---------- launch ----------
extern "C" void kernel_launch(void* const* d_in, const int* in_sizes, int n_in,
                              void* d_out, int out_size, void* d_ws, size_t ws_size,
                              hipStream_t stream)
{
    const float* x        = (const float*)d_in[0];
    const float* pos      = (const float*)d_in[1];
    const float* eattr    = (const float*)d_in[2];
    const int*   ei       = (const int*)d_in[3];
    const int*   cluster1 = (const int*)d_in[4];
    const int*   ei2      = (const int*)d_in[5];
    const int*   cluster2 = (const int*)d_in[6];
    const int*   batch3   = (const int*)d_in[7];
    const float* W1    = (const float*)d_in[9];
    const float* root1 = (const float*)d_in[10];
    const float* b1    = (const float*)d_in[11];
    const float* W2    = (const float*)d_in[12];
    const float* root2 = (const float*)d_in[13];
    const float* b2    = (const float*)d_in[14];
    const float* fc1w  = (const float*)d_in[15];
    const float* fc1b  = (const float*)d_in[16];
    const float* fc2w  = (const float*)d_in[17];
    const float* fc2b  = (const float*)d_in[18];

    const int N  = in_sizes[0];        // x is [N,1]
    const int E  = in_sizes[3] / 2;
    const int E2 = in_sizes[5] / 2;

    char* base = (char*)d_ws;
    size_t off = 0;
    auto alloc = [&](size_t b) { size_t o = off; off += (b + 255) & ~(size_t)255; return o; };
    size_t o_x2b  = alloc((size_t)N * 32 * 4);   // x2bits (atomicMax target)
    size_t o_x3   = alloc((size_t)N * 64 * 4);   // x3bits
    size_t o_cnt1 = alloc((size_t)N * 4);
    size_t o_psum = alloc((size_t)N * 2 * 4);    // possum -> pos2 (in place)
    size_t o_ip1  = alloc((size_t)(N + 1) * 4);
    size_t o_ip2  = alloc((size_t)(N + 1) * 4);
    size_t o_s    = alloc((size_t)NN_NG * 64 * 4);
    size_t o_c    = alloc(64 * 4);
    size_t o_scal = alloc(256);                  // [0]=max cluster1, [1]=maxabs bits
    size_t fixed  = off;                         // memset covers [0, fixed)
    size_t o_x2bf = alloc((size_t)N * 32 * 2);   // x2 bf16 (fully written by fin1)
    size_t o_w2t  = alloc((size_t)64 * 800 * 2); // W2T bf16
    size_t o_r2t  = alloc((size_t)64 * 32 * 2);  // root2T bf16
    size_t o_rec  = alloc((size_t)E2 * 32);      // per-edge basis records (32B)
    (void)ws_size;

    unsigned* x2bits = (unsigned*)(base + o_x2b);
    unsigned* x3bits = (unsigned*)(base + o_x3);
    unsigned* cnt1   = (unsigned*)(base + o_cnt1);
    float*    possum = (float*)(base + o_psum);
    int*      ip1    = (int*)(base + o_ip1);
    int*      ip2    = (int*)(base + o_ip2);
    int*      sbuf   = (int*)(base + o_s);
    unsigned* cbuf   = (unsigned*)(base + o_c);
    unsigned* scal   = (unsigned*)(base + o_scal);
    unsigned short* x2bf = (unsigned short*)(base + o_x2bf);
    unsigned short* W2T  = (unsigned short*)(base + o_w2t);
    unsigned short* r2T  = (unsigned short*)(base + o_r2t);
    float*    rec    = (float*)(base + o_rec);

    hipMemsetAsync(d_ws, 0, fixed, stream);

    int prep_items = 800 * 64 + 64 * 32;
    if (prep_items < N + 1) prep_items = N + 1;
    k_prep<<<(prep_items + 255) / 256, 256, 0, stream>>>(ei, E, ip1, ei2, E2, ip2,
                                                         W2, root2, W2T, r2T, N);

    k_conv1<<<(N + 127) / 128, 512, 0, stream>>>(x, pos, eattr, ei, ei + E, ip1,
                                                 W1, root1, b1, cluster1,
                                                 x2bits, cnt1, possum, &scal[0], N);
    k_fin1<<<(N * 32 + 255) / 256, 256, 0, stream>>>(x2bits, cnt1, x2bf, possum, N);

    int mb = (E2 + 255) / 256;
    if (mb > 256) mb = 256;
    const float* pos2 = (const float*)(base + o_psum);
    k_maxabs<<<mb, 256, 0, stream>>>(ei2, ei2 + E2, E2, pos2, &scal[1]);
    k_basis<<<(E2 + 255) / 256, 256, 0, stream>>>(ei2, ei2 + E2, E2, pos2,
                                                  scal, rec);

    k_conv2<<<256, 1024, 0, stream>>>(rec, ip2, x2bf, W2T, r2T, b2,
                                      cluster2, x3bits, scal, N);

    k_gsum<<<256, 256, 0, stream>>>(x3bits, batch3, sbuf, cbuf, N);
    k_head<<<NN_NG, 128, 0, stream>>>(sbuf, cbuf, fc1w, fc1b, fc2w, fc2b, (float*)d_out);
}

// Round 17
// 210.596 us; speedup vs baseline: 1.1927x; 1.1927x over previous
//
#include <hip/hip_runtime.h>
#include <math.h>

// GCN1: 2x SplineConv (deg-1 B-spline, KS=5, dim=2) + graclus max-pools + MLP head.
#define NN_F1 32
#define NN_F2 64
#define NN_FH 128
#define NN_NC 10
#define NN_NG 50
#define ACCI 808           // int32 A-row stride (800 used + 8 pad)
#define FXS  1048576.0f    // 2^20 fixed-point scale (conv scatters)
#define FXI  (1.0f/1048576.0f)
#define GXS  65536.0f      // 2^16 fixed-point scale (graph mean-pool)
#define GXI  (1.0f/65536.0f)

typedef __attribute__((ext_vector_type(8))) short short8v;   // 8 bf16 = 4 VGPRs
typedef __attribute__((ext_vector_type(4))) float f32x4;

// ---------- helpers ----------
__device__ __forceinline__ unsigned fkey(float f) {
    unsigned u = __float_as_uint(f);
    return (u & 0x80000000u) ? ~u : (u | 0x80000000u);
}
__device__ __forceinline__ float funkey(unsigned k) {
    return (k & 0x80000000u) ? __uint_as_float(k & 0x7fffffffu) : __uint_as_float(~k);
}
// pack two floats -> two bf16 (RNE)
__device__ __forceinline__ unsigned bfp2(float a, float b) {
    unsigned ua = __float_as_uint(a), ub = __float_as_uint(b);
    ua += 0x7fffu + ((ua >> 16) & 1u);
    ub += 0x7fffu + ((ub >> 16) & 1u);
    return (ua >> 16) | (ub & 0xffff0000u);
}
__device__ __forceinline__ unsigned short bf1(float a) {
    unsigned u = __float_as_uint(a);
    u += 0x7fffu + ((u >> 16) & 1u);
    return (unsigned short)(u >> 16);
}

// degree-1 open B-spline, KS=5/dim, dim=2 — FLAT taps + products.
// Order matches reference reshape (verified rounds 0-16).
__device__ __forceinline__ void spline_basis(float ax, float ay, int wi[4], float bb[4]) {
    float v0 = ax * 4.0f, v1 = ay * 4.0f;
    float l0 = floorf(v0), l1 = floorf(v1);
    float f0 = v0 - l0, f1 = v1 - l1;
    int i0a = (int)l0, i1a = (int)l1;
    int i00 = min(max(i0a, 0), 4), i01 = min(max(i0a + 1, 0), 4);
    int i10 = min(max(i1a, 0), 4), i11 = min(max(i1a + 1, 0), 4);
    float b00 = 1.0f - f0, b01 = f0, b10 = 1.0f - f1, b11 = f1;
    wi[0] = i00 + 5 * i10; bb[0] = b00 * b10;
    wi[1] = i00 + 5 * i11; bb[1] = b00 * b11;
    wi[2] = i01 + 5 * i10; bb[2] = b01 * b10;
    wi[3] = i01 + 5 * i11; bb[3] = b01 * b11;
}

// ---------- K0: fused prep — both CSR indptrs + W2/root2 bf16 transpose ----------
__global__ __launch_bounds__(256) void k_prep(
    const int* __restrict__ row1, int E, int* __restrict__ ip1,
    const int* __restrict__ row2, int E2, int* __restrict__ ip2,
    const float* __restrict__ W2, const float* __restrict__ root2,
    unsigned short* __restrict__ W2T, unsigned short* __restrict__ r2T, int N)
{
    int i = blockIdx.x * 256 + threadIdx.x;
    if (i <= N) {
        if (i == N) { ip1[N] = E; ip2[N] = E2; }
        else {
            int l = 0, r = E;
            while (l < r) { int m = (l + r) >> 1; if (row1[m] < i) l = m + 1; else r = m; }
            ip1[i] = l;
            l = 0; r = E2;
            while (l < r) { int m = (l + r) >> 1; if (row2[m] < i) l = m + 1; else r = m; }
            ip2[i] = l;
        }
    }
    if (i < 800 * 64) {
        int k = i >> 6, n = i & 63;
        W2T[n * 800 + k] = bf1(W2[i]);
    } else if (i < 800 * 64 + 64 * 32) {
        int j = i - 800 * 64;
        int o = j >> 5, f = j & 31;
        r2T[o * 32 + f] = bf1(root2[f * 64 + o]);
    }
}

// ---------- K1: conv1, two-phase, 512 threads / 128-node tile ----------
__device__ __forceinline__ void scat1(int* __restrict__ gacc, int r,
                                      float2 ea, float xs) {
    int wi[4]; float bb[4];
    spline_basis(1.0f - ea.x, 1.0f - ea.y, wi, bb);
    int* bp = gacc + r * 26;
    atomicAdd((unsigned*)(bp + wi[0]), (unsigned)(int)(bb[0] * xs));
    atomicAdd((unsigned*)(bp + wi[1]), (unsigned)(int)(bb[1] * xs));
    atomicAdd((unsigned*)(bp + wi[2]), (unsigned)(int)(bb[2] * xs));
    atomicAdd((unsigned*)(bp + wi[3]), (unsigned)(int)(bb[3] * xs));
}
__global__ __launch_bounds__(512) void k_conv1(
    const float* __restrict__ x, const float* __restrict__ pos,
    const float* __restrict__ eattr,
    const int* __restrict__ ei0, const int* __restrict__ ei1,
    const int* __restrict__ indptr,
    const float* __restrict__ W1, const float* __restrict__ root1,
    const float* __restrict__ b1, const int* __restrict__ cluster1,
    unsigned* __restrict__ x2bits, unsigned* __restrict__ cnt1,
    float* __restrict__ possum, unsigned* __restrict__ n2slot, int N)
{
    __shared__ float w1s[25 * NN_F1];
    __shared__ float r1s[NN_F1], b1s[NN_F1];
    __shared__ int   gacc[128 * 26];      // fixed-point taps, stride 26 (bank-spread)
    __shared__ float invdeg[128], xds[128];
    __shared__ int   cls[128];
    __shared__ unsigned blkmax;
    int t = threadIdx.x;
    for (int i = t; i < 25 * NN_F1; i += 512) w1s[i] = W1[i];
    if (t < NN_F1) { r1s[t] = root1[t]; b1s[t] = b1[t]; }
    if (t == 0) blkmax = 0u;
    int4* gz = (int4*)gacc;
    for (int i = t; i < 128 * 26 / 4; i += 512) gz[i] = make_int4(0, 0, 0, 0);
    __syncthreads();                      // gacc zeroed, blkmax=0 visible

    int nb0 = blockIdx.x * 128;
    if (t < 128) {
        int d = nb0 + t;
        if (d < N) {
            int lo = indptr[d], hi = indptr[d + 1];
            invdeg[t] = FXI / (float)max(hi - lo, 1);   // descale folded in
            xds[t] = x[d];
            int c = cluster1[d];
            cls[t] = c;
            atomicAdd(&cnt1[c], 1u);
            atomicAdd(&possum[2 * c], pos[2 * d]);
            atomicAdd(&possum[2 * c + 1], pos[2 * d + 1]);
            atomicMax(&blkmax, (unsigned)c);
        }
    }

    // edge-parallel scatter over the block's contiguous CSR range, 2x unrolled
    int e0 = indptr[nb0], e1 = indptr[min(nb0 + 128, N)];
    int e = e0 + t;
    for (; e + 512 < e1; e += 1024) {
        int ra = ei0[e] - nb0,       sa = ei1[e];
        int rb = ei0[e + 512] - nb0, sb = ei1[e + 512];
        float2 eaa = ((const float2*)eattr)[e];
        float2 eab = ((const float2*)eattr)[e + 512];
        float xa = x[sa] * FXS;
        float xb = x[sb] * FXS;
        scat1(gacc, ra, eaa, xa);
        scat1(gacc, rb, eab, xb);
    }
    if (e < e1) {
        int ra = ei0[e] - nb0, sa = ei1[e];
        scat1(gacc, ra, ((const float2*)eattr)[e], x[sa] * FXS);
    }
    __syncthreads();                      // scatter + node-init complete
    if (t == 0) atomicMax(n2slot, blkmax);

    // Phase B: 16 groups x 32 lanes; lane o owns output feature o.
    int grp = t >> 5, o = t & 31;
    float wreg[25];
#pragma unroll
    for (int k = 0; k < 25; ++k) wreg[k] = w1s[k * NN_F1 + o];
    float ro = r1s[o], bo = b1s[o];
    int nloc = min(128, N - nb0);
    for (int i = grp; i < nloc; i += 16) {
        float a = 0.f;
#pragma unroll
        for (int k = 0; k < 25; ++k) a += (float)gacc[i * 26 + k] * wreg[k];
        float h = a * invdeg[i] + xds[i] * ro + bo;
        h = h > 0.f ? h : expm1f(h);
        atomicMax(&x2bits[(size_t)cls[i] * NN_F1 + o], fkey(h));
    }
}

// ---------- K2: finalize x2 -> bf16 (zero empties), pos2 = possum/cnt ----------
__global__ __launch_bounds__(256) void k_fin1(const unsigned* __restrict__ x2b,
                                              const unsigned* __restrict__ cnt1,
                                              unsigned short* __restrict__ x2bf,
                                              float* __restrict__ possum, int N)
{
    int i = blockIdx.x * 256 + threadIdx.x;
    int n = i >> 5, o = i & 31;
    if (n >= N) return;
    unsigned cnt = cnt1[n];
    float v = cnt ? funkey(x2b[i]) : 0.0f;
    x2bf[i] = bf1(v);
    if (o < 2) {
        float p = possum[2 * n + o];
        possum[2 * n + o] = p / (float)max(cnt, 1u);
    }
}

// ---------- K3: global max|cart| over pooled edges (block-reduced, 1 atomic/block) ----------
__global__ __launch_bounds__(256) void k_maxabs(const int* __restrict__ r0,
                                                const int* __restrict__ r1, int E2,
                                                const float* __restrict__ pos2,
                                                unsigned* __restrict__ maxbits)
{
    __shared__ float wmax[4];
    float m = 0.f;
    for (int e = blockIdx.x * 256 + threadIdx.x; e < E2; e += gridDim.x * 256) {
        int a = r0[e], b = r1[e];
        float cx = pos2[2 * a] - pos2[2 * b];
        float cy = pos2[2 * a + 1] - pos2[2 * b + 1];
        m = fmaxf(m, fmaxf(fabsf(cx), fabsf(cy)));
    }
    for (int off = 32; off; off >>= 1) m = fmaxf(m, __shfl_down(m, off));
    if ((threadIdx.x & 63) == 0) wmax[threadIdx.x >> 6] = m;
    __syncthreads();
    if (threadIdx.x == 0) {
        m = fmaxf(fmaxf(wmax[0], wmax[1]), fmaxf(wmax[2], wmax[3]));
        atomicMax(maxbits, __float_as_uint(m));   // all values >= 0: bit-compare ok
    }
}

// ---------- K3c: per-edge basis records (32B): {bb*2^20 f32x4, s, wjpack, d, pad} ----------
__global__ __launch_bounds__(256) void k_basis(
    const int* __restrict__ r0, const int* __restrict__ r1, int E2,
    const float* __restrict__ pos2, const unsigned* __restrict__ scal,
    float* __restrict__ rec)
{
    int e = blockIdx.x * 256 + threadIdx.x;
    if (e >= E2) return;
    float denom = 2.0f * __uint_as_float(scal[1]);
    int d = r0[e], s = r1[e];          // true edge is (s -> d): cart = pos2[s] - pos2[d]
    float ax = (pos2[2 * s] - pos2[2 * d]) / denom + 0.5f;
    float ay = (pos2[2 * s + 1] - pos2[2 * d + 1]) / denom + 0.5f;
    int wi[4]; float bb[4];
    spline_basis(ax, ay, wi, bb);
    unsigned wj = (unsigned)wi[0] | ((unsigned)wi[1] << 8)
                | ((unsigned)wi[2] << 16) | ((unsigned)wi[3] << 24);
    float* rp = rec + (size_t)e * 8;
    *(float4*)rp = make_float4(bb[0] * FXS, bb[1] * FXS, bb[2] * FXS, bb[3] * FXS);
    int4 meta = make_int4(s, (int)wj, d, 0);
    *(int4*)(rp + 4) = meta;
}

// ---------- K4: conv2 FUSED scatter + MFMA GEMM + epilogue (r13-proven form) ----------
// Block = 16 nodes, 1024 threads (16 waves): 2 blocks/CU = 32 waves/CU.
// Phase 1: 64 subgroups x 16 lanes take CONTIGUOUS slices of the block's CSR
// range; lane owns feature pair 2f/2f+1 (one u32 gather/edge); Q11.20 taps into
// the tap*32+f layout via fire-and-forget ds_add_u32 (~2.78M conflicts,
// not time-binding). Phase 2 on waves 0-3: K=800 MFMA loop with per-iter
// int->bf16 pack — the pack VALU doubles as latency-hiding ILP between
// dependent LDS reads (removing it measured SLOWER, r8/r11/r16). Fused epilogue
// (/deg, +x2@root2 via MFMA, +b2, elu, pool2 atomicMax).
// Measured-rejected alternatives (r8-r16): strided assignment (+11us, bank
// conflicts), in-place tile convert (+11us, lost ILP), 16-wave split GEMM
// (+8us, barrier cost), XCD swizzle (null; -2.5% FETCH only), persistent
// producer-consumer pipeline (+43us, halved waves/CU).
__device__ __forceinline__ short8v ld_frag(const unsigned short* p) {
    short8v a;
    ((unsigned long long*)&a)[0] = *(const unsigned long long*)(p);        // k+0..3
    ((unsigned long long*)&a)[1] = *(const unsigned long long*)(p + 16);   // k+16..19
    return a;
}
__device__ __forceinline__ short8v pack_frag_i(int4 a, int4 b) {
    union { unsigned u[4]; short8v s; } r;
    r.u[0] = bfp2((float)a.x * FXI, (float)a.y * FXI);
    r.u[1] = bfp2((float)a.z * FXI, (float)a.w * FXI);
    r.u[2] = bfp2((float)b.x * FXI, (float)b.y * FXI);
    r.u[3] = bfp2((float)b.z * FXI, (float)b.w * FXI);
    return r.s;
}
__device__ __forceinline__ void scat2(int* __restrict__ accs, int r, unsigned wj,
                                      float4 bb, float xl, float xh, int f2) {
    int* base = accs + r * ACCI + f2;
    int* a0 = base + ((wj & 31u) << 5);
    int* a1 = base + (((wj >> 8) & 31u) << 5);
    int* a2 = base + (((wj >> 16) & 31u) << 5);
    int* a3 = base + (((wj >> 24) & 31u) << 5);
    atomicAdd((unsigned*)a0,       (unsigned)(int)(bb.x * xl));
    atomicAdd((unsigned*)(a0 + 1), (unsigned)(int)(bb.x * xh));
    atomicAdd((unsigned*)a1,       (unsigned)(int)(bb.y * xl));
    atomicAdd((unsigned*)(a1 + 1), (unsigned)(int)(bb.y * xh));
    atomicAdd((unsigned*)a2,       (unsigned)(int)(bb.z * xl));
    atomicAdd((unsigned*)(a2 + 1), (unsigned)(int)(bb.z * xh));
    atomicAdd((unsigned*)a3,       (unsigned)(int)(bb.w * xl));
    atomicAdd((unsigned*)(a3 + 1), (unsigned)(int)(bb.w * xh));
}
__global__ __launch_bounds__(1024) void k_conv2(
    const float* __restrict__ rec, const int* __restrict__ indptr2,
    const unsigned short* __restrict__ x2bf, const unsigned short* __restrict__ W2T,
    const unsigned short* __restrict__ r2T, const float* __restrict__ b2,
    const int* __restrict__ cluster2, unsigned* __restrict__ x3bits,
    const unsigned* __restrict__ scal, int N)
{
    __shared__ int accs[16 * ACCI];       // fixed-point A-tile [16 rows][800+8]
    __shared__ float degl[16];
    int n2 = (int)scal[0] + 1;
    int nb = blockIdx.x * 16;
    if (nb >= n2) return;                 // block-uniform exit (before any barrier)
    int t = threadIdx.x;

    // zero acc + per-node degrees
    int4* az = (int4*)accs;
    for (int j = t; j < 16 * ACCI / 4; j += 1024) az[j] = make_int4(0, 0, 0, 0);
    if (t < 16) {
        int d = min(nb + t, N - 1);
        degl[t] = (float)max(indptr2[d + 1] - indptr2[d], 1);
    }
    __syncthreads();

    // ---- phase 1: contiguous-slice edge-parallel scatter, 2x unrolled ----
    int sg = t >> 4, f2 = (t & 15) << 1;  // subgroup 0..63, feature pair 2f/2f+1
    int e0 = indptr2[nb];
    int e1 = indptr2[min(nb + 16, N)];
    int len = ((e1 - e0) + 63) >> 6;      // slice per subgroup (contiguous)
    int lo = e0 + sg * len;
    int hi = min(lo + len, e1);
    int e = lo;
    for (; e + 2 <= hi; e += 2) {
        const float* rp0 = rec + (size_t)e * 8;
        const float* rp1 = rp0 + 8;
        float4 bb0 = *(const float4*)rp0;
        int4  m0  = *(const int4*)(rp0 + 4);
        float4 bb1 = *(const float4*)rp1;
        int4  m1  = *(const int4*)(rp1 + 4);
        unsigned xa = *(const unsigned*)(x2bf + (size_t)m0.x * 32 + f2);
        unsigned xb = *(const unsigned*)(x2bf + (size_t)m1.x * 32 + f2);
        float xla = __uint_as_float(xa << 16), xha = __uint_as_float(xa & 0xffff0000u);
        float xlb = __uint_as_float(xb << 16), xhb = __uint_as_float(xb & 0xffff0000u);
        scat2(accs, m0.z - nb, (unsigned)m0.y, bb0, xla, xha, f2);
        scat2(accs, m1.z - nb, (unsigned)m1.y, bb1, xlb, xhb, f2);
    }
    if (e < hi) {
        const float* rp0 = rec + (size_t)e * 8;
        float4 bb0 = *(const float4*)rp0;
        int4  m0  = *(const int4*)(rp0 + 4);
        unsigned xa = *(const unsigned*)(x2bf + (size_t)m0.x * 32 + f2);
        float xla = __uint_as_float(xa << 16), xha = __uint_as_float(xa & 0xffff0000u);
        scat2(accs, m0.z - nb, (unsigned)m0.y, bb0, xla, xha, f2);
    }
    __syncthreads();
    if (t >= 256) return;                 // waves 4-15 done (scatter only)

    // ---- phase 2: per-wave 16x16 col-block GEMM (per-iter pack = free ILP) ----
    int w = t >> 6, l = t & 63;
    int lg = l >> 4, lr = l & 15;
    int c0 = w * 16;
    const int* arow = accs + lr * ACCI;
    const unsigned short* pb = W2T + (size_t)(c0 + lr) * 800 + 4 * lg;

    f32x4 s4 = {0.f, 0.f, 0.f, 0.f};
    for (int kk = 0; kk < 800; kk += 32) {
        int4 a0 = *(const int4*)(arow + kk + 4 * lg);
        int4 a1 = *(const int4*)(arow + kk + 16 + 4 * lg);
        short8v af = pack_frag_i(a0, a1);
        short8v bf = ld_frag(pb + kk);
        s4 = __builtin_amdgcn_mfma_f32_16x16x32_bf16(af, bf, s4, 0, 0, 0);
    }

    int r0g = nb + 4 * lg;
#pragma unroll
    for (int i = 0; i < 4; ++i) {
        int gr = r0g + i;
        float invd = (gr < n2) ? 1.0f / degl[4 * lg + i] : 0.0f;
        s4[i] *= invd;
    }
    int ar2 = nb + lr; if (ar2 > N - 1) ar2 = N - 1;
    short8v a2f = ld_frag(x2bf + (size_t)ar2 * 32 + 4 * lg);
    s4 = __builtin_amdgcn_mfma_f32_16x16x32_bf16(
             a2f, ld_frag(r2T + (size_t)(c0 + lr) * 32 + 4 * lg), s4, 0, 0, 0);

    float bs = b2[c0 + lr];
#pragma unroll
    for (int i = 0; i < 4; ++i) {
        int gr = r0g + i;
        if (gr >= n2) continue;
        float h = s4[i] + bs;
        h = h > 0.f ? h : expm1f(h);
        atomicMax(&x3bits[(size_t)cluster2[gr] * 64 + c0 + lr], fkey(h));
    }
}

// ---------- K6: graph mean-pool (INT fixed-point LDS histogram, native atomics) ----------
__global__ __launch_bounds__(256) void k_gsum(const unsigned* __restrict__ x3bits,
                                              const int* __restrict__ batch3,
                                              int* __restrict__ sbuf,
                                              unsigned* __restrict__ cbuf, int N)
{
    __shared__ int sl[NN_NG * 64];
    __shared__ unsigned clh[NN_NG];
    int t = threadIdx.x;
    for (int i = t; i < NN_NG * 64; i += 256) sl[i] = 0;
    if (t < NN_NG) clh[t] = 0u;
    __syncthreads();
    int o = t & 63, rsub = t >> 6;
    for (int i0 = blockIdx.x * 4; i0 < N; i0 += gridDim.x * 4) {
        int i = i0 + rsub;
        if (i < N) {
            int g = batch3[i];
            if (g < NN_NG) {   // dummy graph id NG is dropped
                float v = funkey(x3bits[(size_t)i * 64 + o]);
                atomicAdd((unsigned*)&sl[g * 64 + o], (unsigned)(int)(v * GXS));
                if (o == 0) atomicAdd(&clh[g], 1u);
            }
        }
    }
    __syncthreads();
    for (int i = t; i < NN_NG * 64; i += 256)
        atomicAdd((unsigned*)&sbuf[i], (unsigned)sl[i]);
    if (t < NN_NG) atomicAdd(&cbuf[t], clh[t]);
}

// ---------- K7: MLP head + log_softmax ----------
__global__ __launch_bounds__(128) void k_head(const int* __restrict__ sbuf,
                                              const unsigned* __restrict__ cbuf,
                                              const float* __restrict__ fc1w,
                                              const float* __restrict__ fc1b,
                                              const float* __restrict__ fc2w,
                                              const float* __restrict__ fc2b,
                                              float* __restrict__ out)
{
    __shared__ float xg[64], hl[NN_FH], ll[NN_NC];
    int g = blockIdx.x, t = threadIdx.x;
    if (t < 64) xg[t] = (float)sbuf[g * 64 + t] * GXI / (float)max(cbuf[g], 1u);
    __syncthreads();
    float a = fc1b[t];
    for (int f = 0; f < 64; ++f) a += xg[f] * fc1w[f * NN_FH + t];
    hl[t] = a > 0.f ? a : expm1f(a);
    __syncthreads();
    if (t < NN_NC) {
        float l = fc2b[t];
        for (int h = 0; h < NN_FH; ++h) l += hl[h] * fc2w[h * NN_NC + t];
        ll[t] = l;
    }
    __syncthreads();
    if (t < NN_NC) {
        float m = ll[0];
        for (int j = 1; j < NN_NC; ++j) m = fmaxf(m, ll[j]);
        float sum = 0.f;
        for (int j = 0; j < NN_NC; ++j) sum += expf(ll[j] - m);
        out[g * NN_NC + t] = ll[t] - m - logf(sum);
    }
}

// ---------- launch ----------
extern "C" void kernel_launch(void* const* d_in, const int* in_sizes, int n_in,
                              void* d_out, int out_size, void* d_ws, size_t ws_size,
                              hipStream_t stream)
{
    const float* x        = (const float*)d_in[0];
    const float* pos      = (const float*)d_in[1];
    const float* eattr    = (const float*)d_in[2];
    const int*   ei       = (const int*)d_in[3];
    const int*   cluster1 = (const int*)d_in[4];
    const int*   ei2      = (const int*)d_in[5];
    const int*   cluster2 = (const int*)d_in[6];
    const int*   batch3   = (const int*)d_in[7];
    const float* W1    = (const float*)d_in[9];
    const float* root1 = (const float*)d_in[10];
    const float* b1    = (const float*)d_in[11];
    const float* W2    = (const float*)d_in[12];
    const float* root2 = (const float*)d_in[13];
    const float* b2    = (const float*)d_in[14];
    const float* fc1w  = (const float*)d_in[15];
    const float* fc1b  = (const float*)d_in[16];
    const float* fc2w  = (const float*)d_in[17];
    const float* fc2b  = (const float*)d_in[18];

    const int N  = in_sizes[0];        // x is [N,1]
    const int E  = in_sizes[3] / 2;
    const int E2 = in_sizes[5] / 2;

    char* base = (char*)d_ws;
    size_t off = 0;
    auto alloc = [&](size_t b) { size_t o = off; off += (b + 255) & ~(size_t)255; return o; };
    size_t o_x2b  = alloc((size_t)N * 32 * 4);   // x2bits (atomicMax target)
    size_t o_x3   = alloc((size_t)N * 64 * 4);   // x3bits
    size_t o_cnt1 = alloc((size_t)N * 4);
    size_t o_psum = alloc((size_t)N * 2 * 4);    // possum -> pos2 (in place)
    size_t o_ip1  = alloc((size_t)(N + 1) * 4);
    size_t o_ip2  = alloc((size_t)(N + 1) * 4);
    size_t o_s    = alloc((size_t)NN_NG * 64 * 4);
    size_t o_c    = alloc(64 * 4);
    size_t o_scal = alloc(256);                  // [0]=max cluster1, [1]=maxabs bits
    size_t fixed  = off;                         // memset covers [0, fixed)
    size_t o_x2bf = alloc((size_t)N * 32 * 2);   // x2 bf16 (fully written by fin1)
    size_t o_w2t  = alloc((size_t)64 * 800 * 2); // W2T bf16
    size_t o_r2t  = alloc((size_t)64 * 32 * 2);  // root2T bf16
    size_t o_rec  = alloc((size_t)E2 * 32);      // per-edge basis records (32B)
    (void)ws_size;

    unsigned* x2bits = (unsigned*)(base + o_x2b);
    unsigned* x3bits = (unsigned*)(base + o_x3);
    unsigned* cnt1   = (unsigned*)(base + o_cnt1);
    float*    possum = (float*)(base + o_psum);
    int*      ip1    = (int*)(base + o_ip1);
    int*      ip2    = (int*)(base + o_ip2);
    int*      sbuf   = (int*)(base + o_s);
    unsigned* cbuf   = (unsigned*)(base + o_c);
    unsigned* scal   = (unsigned*)(base + o_scal);
    unsigned short* x2bf = (unsigned short*)(base + o_x2bf);
    unsigned short* W2T  = (unsigned short*)(base + o_w2t);
    unsigned short* r2T  = (unsigned short*)(base + o_r2t);
    float*    rec    = (float*)(base + o_rec);

    hipMemsetAsync(d_ws, 0, fixed, stream);

    int prep_items = 800 * 64 + 64 * 32;
    if (prep_items < N + 1) prep_items = N + 1;
    k_prep<<<(prep_items + 255) / 256, 256, 0, stream>>>(ei, E, ip1, ei2, E2, ip2,
                                                         W2, root2, W2T, r2T, N);

    k_conv1<<<(N + 127) / 128, 512, 0, stream>>>(x, pos, eattr, ei, ei + E, ip1,
                                                 W1, root1, b1, cluster1,
                                                 x2bits, cnt1, possum, &scal[0], N);
    k_fin1<<<(N * 32 + 255) / 256, 256, 0, stream>>>(x2bits, cnt1, x2bf, possum, N);

    int mb = (E2 + 255) / 256;
    if (mb > 256) mb = 256;
    const float* pos2 = (const float*)(base + o_psum);
    k_maxabs<<<mb, 256, 0, stream>>>(ei2, ei2 + E2, E2, pos2, &scal[1]);
    k_basis<<<(E2 + 255) / 256, 256, 0, stream>>>(ei2, ei2 + E2, E2, pos2,
                                                  scal, rec);

    k_conv2<<<(N + 15) / 16, 1024, 0, stream>>>(rec, ip2, x2bf, W2T, r2T, b2,
                                                cluster2, x3bits, scal, N);

    k_gsum<<<256, 256, 0, stream>>>(x3bits, batch3, sbuf, cbuf, N);
    k_head<<<NN_NG, 128, 0, stream>>>(sbuf, cbuf, fc1w, fc1b, fc2w, fc2b, (float*)d_out);
}